// Round 1
// baseline (276.087 us; speedup 1.0000x reference)
//
#include <hip/hip_runtime.h>

// Problem constants (fixed by reference): B=32, N=512, M=64 grid coords,
// 2*SIGMA^2 = 128, BG_RATIO = 0.15, output [32][513][4096] fp32.
#define NPTS 512
#define KINV (-0.0078125f)   // -1/(2*sigma^2) = -1/128, exact in fp32

// Kernel 1: one block per (batch, i). Computes per-column softmax denominator
// S[i][j] = sum_n exp(-(ydis[n,i]+xdis[n,j])/128) + bg, tracks min_dis directly,
// writes 1/S to workspace and the background output row (row 512).
__global__ __launch_bounds__(256) void k_denom(
    const float* __restrict__ pts,    // [32][512][2]
    const float* __restrict__ st,     // [32]
    const float* __restrict__ cood,   // [64]
    float* __restrict__ out,          // [32][513][4096]
    float* __restrict__ rinv)         // ws: [32][64][64]
{
    __shared__ float s_x[NPTS];
    __shared__ float s_yd[NPTS];
    __shared__ float s_sum[4][64];
    __shared__ float s_min[4][64];

    const int b   = blockIdx.x >> 6;
    const int i   = blockIdx.x & 63;
    const int tid = threadIdx.x;
    const float ci = cood[i];

    // Stage x coords and (y - c_i)^2 for all 512 points.
    for (int t = tid; t < NPTS; t += 256) {
        float2 p = ((const float2*)pts)[b * NPTS + t];
        s_x[t] = p.x;
        float yd = p.y - ci;
        s_yd[t] = yd * yd;
    }
    __syncthreads();

    // Thread owns column j, quarter q of the n-range. LDS reads are
    // wave-uniform in n (broadcast, conflict-free).
    const int j = tid & 63;
    const int q = tid >> 6;
    const float cj = cood[j];
    float sum = 0.0f;
    float mn  = 3.4e38f;
    const int n0 = q * 128;
    #pragma unroll 8
    for (int n = n0; n < n0 + 128; ++n) {
        float xd = s_x[n] - cj;
        float a  = fmaf(xd, xd, s_yd[n]);     // full distance^2
        sum += __expf(a * KINV);
        mn = fminf(mn, a);
    }
    s_sum[q][j] = sum;
    s_min[q][j] = mn;
    __syncthreads();

    if (tid < 64) {
        float S = (s_sum[0][tid] + s_sum[1][tid]) + (s_sum[2][tid] + s_sum[3][tid]);
        float m = fminf(fminf(s_min[0][tid], s_min[1][tid]),
                        fminf(s_min[2][tid], s_min[3][tid]));
        m = fmaxf(m, 0.0f);                    // reference's clip(min_dis, 0)
        float dd = st[b] * 0.15f;              // BG_RATIO
        float bd = dd - sqrtf(m);
        float bg = __expf(bd * bd * KINV);
        S += bg;
        float r = 1.0f / S;
        rinv[b * 4096 + i * 64 + tid] = r;
        out[(size_t)(b * 513 + 512) * 4096 + i * 64 + tid] = bg * r;
    }
}

// Kernel 2: one block per (batch, 16-row chunk). out[n][i*64+j] =
// ey[n,i] * ex[n,j] * rinv[i,j], streamed as fully-coalesced float4 stores.
__global__ __launch_bounds__(256) void k_write(
    const float* __restrict__ pts,
    const float* __restrict__ cood,
    const float* __restrict__ rinv,
    float* __restrict__ out)
{
    __shared__ float s_rinv[4096];     // 16 KB
    __shared__ float s_ex[16 * 64];    // 4 KB
    __shared__ float s_ey[16 * 64];    // 4 KB

    const int b   = blockIdx.x >> 5;
    const int n0  = (blockIdx.x & 31) * 16;
    const int tid = threadIdx.x;

    // Stage reciprocal denominators (coalesced float4 from L2-resident ws).
    const float4* rsrc = (const float4*)(rinv + b * 4096);
    for (int t = tid; t < 1024; t += 256)
        ((float4*)s_rinv)[t] = rsrc[t];

    // Compute ex/ey for this 16-row chunk (2048 exps per block).
    for (int t = tid; t < 1024; t += 256) {
        int nl = t >> 6;
        int jj = t & 63;
        float2 p = ((const float2*)pts)[b * NPTS + n0 + nl];
        float c  = cood[jj];
        float xd = p.x - c;
        float yd = p.y - c;
        s_ex[t] = __expf(xd * xd * KINV);
        s_ey[t] = __expf(yd * yd * KINV);
    }
    __syncthreads();

    // 16 rows x 4096 floats = 16384 float4 / 256 threads = 64 iters.
    // Consecutive tid -> consecutive float4: each pass writes one
    // contiguous 4 KB stretch (1 KB per wave-store).
    float4* dst = (float4*)(out + (size_t)(b * 513 + n0) * 4096);
    #pragma unroll 4
    for (int it = 0; it < 64; ++it) {
        int idx = it * 256 + tid;
        int nl  = idx >> 10;       // local row
        int c4  = idx & 1023;      // float4 column
        int ii  = c4 >> 4;         // y-grid index
        int j4  = c4 & 15;         // x-grid float4 index
        float4 ex4 = ((const float4*)s_ex)[nl * 16 + j4];
        float4 r4  = ((const float4*)s_rinv)[ii * 16 + j4];
        float  ey  = s_ey[nl * 64 + ii];
        float4 o;
        o.x = ey * ex4.x * r4.x;
        o.y = ey * ex4.y * r4.y;
        o.z = ey * ex4.z * r4.z;
        o.w = ey * ex4.w * r4.w;
        dst[idx] = o;
    }
}

extern "C" void kernel_launch(void* const* d_in, const int* in_sizes, int n_in,
                              void* d_out, int out_size, void* d_ws, size_t ws_size,
                              hipStream_t stream) {
    const float* pts  = (const float*)d_in[0];   // points [32][512][2]
    const float* st   = (const float*)d_in[1];   // st_sizes [32]
    const float* cood = (const float*)d_in[2];   // cood [64]
    float* out  = (float*)d_out;                 // [32][513][4096] fp32
    float* rinv = (float*)d_ws;                  // 512 KB scratch

    k_denom<<<dim3(2048), dim3(256), 0, stream>>>(pts, st, cood, out, rinv);
    k_write<<<dim3(1024), dim3(256), 0, stream>>>(pts, cood, rinv, out);
}